// Round 8
// baseline (609.851 us; speedup 1.0000x reference)
//
#include <hip/hip_runtime.h>
#include <hip/hip_bf16.h>

// Bahdanau attention, restructured:
//   tanh_in[b,t,k] = e[b,t,:]@(U@Wa) + cvec[b,k]   (one 131072x512x512 bf16 GEMM)
//   cij[b,t] = sum_k tanh(tanh_in)*V[k]            (fused epilogue)
//   alphas = softmax(cij); out = sum_t alphas*e
// Shapes: B=32 T=4096 D=512 H=512.
//
// R8: the m97 rung, bought honestly. R5-R7 (A converted fp32->bf16 through a
// VGPR round-trip in the GEMM) all plateau ~165-175us = the m93 rung (~500 TF).
// New: k_conv pre-converts e to bf16 ONCE (pure stream), so the GEMM can stage
// BOTH operands via global_load_lds width=16 into LDS (m97 structure: 128x128
// tile, BK=64, 2-barrier K-loop, proven 874-912 TF). k_wsum reads the bf16
// copy (134 MB vs 268). Fixed harness overhead per replay: ~160us ws poison +
// input restore.

#define BB 32
#define TT 4096
#define DD 512
#define HH 512
#define MM (BB * TT)

typedef short s16x8 __attribute__((ext_vector_type(8)));
typedef float f32x4 __attribute__((ext_vector_type(4)));

union FU { float f; unsigned u; };

static __device__ __forceinline__ unsigned short f2bf_rne(float x) {
    FU v; v.f = x;
    unsigned u = v.u;
    u = u + 0x7fffu + ((u >> 16) & 1u);
    return (unsigned short)(u >> 16);
}

static __device__ __forceinline__ float tanh_fast(float x) {
    float e = __expf(2.0f * x);
    return 1.0f - 2.0f * __builtin_amdgcn_rcpf(e + 1.0f);
}

// async global->LDS, 16B/lane. LDS dest = wave-uniform base + lane*16.
static __device__ __forceinline__ void gload_lds16(const void* g, void* l) {
    __builtin_amdgcn_global_load_lds(
        (const __attribute__((address_space(1))) unsigned int*)g,
        (__attribute__((address_space(3))) unsigned int*)l, 16, 0, 0);
}

// ---------------------------------------------------------------------------
// k_conv: e fp32 -> bf16 (RNE), pure stream. 8,388,608 groups of 8 floats;
// 4096 blocks x 256 thr x 8 groups, coalesced per iteration.
__global__ void k_conv(const float* __restrict__ e, unsigned short* __restrict__ ebf) {
    size_t idx = (size_t)blockIdx.x * 256 + threadIdx.x;
    #pragma unroll
    for (int it = 0; it < 8; ++it) {
        size_t g = idx + (size_t)it * 1048576;
        const float* p = e + g * 8;
        float4 v0 = *(const float4*)p;
        float4 v1 = *(const float4*)(p + 4);
        union { unsigned short us[8]; uint4 u4; } o;
        o.us[0] = f2bf_rne(v0.x); o.us[1] = f2bf_rne(v0.y);
        o.us[2] = f2bf_rne(v0.z); o.us[3] = f2bf_rne(v0.w);
        o.us[4] = f2bf_rne(v1.x); o.us[5] = f2bf_rne(v1.y);
        o.us[6] = f2bf_rne(v1.z); o.us[7] = f2bf_rne(v1.w);
        *(uint4*)(ebf + g * 8) = o.u4;
    }
}

// ---------------------------------------------------------------------------
// k_prep, 96 blocks x 256 thr:
//  blocks 0..31  : cvec[b,:] = (hs[b]@W + bias)@Wa + ba   (per-batch, no atomics)
//  blocks 32..95 : UWaT[n][d] = bf16(sum_h U[d,h]*Wa[h,n])  -- row-major [n][k],
//                  the same layout as ebf rows, for global_load_lds staging.
__global__ void k_prep(const float* __restrict__ hs, const float* __restrict__ W,
                       const float* __restrict__ bias, const float* __restrict__ Wa,
                       const float* __restrict__ ba, const float* __restrict__ U,
                       float* __restrict__ cvec, unsigned short* __restrict__ UWaT) {
    int bi = blockIdx.x;
    int tid = threadIdx.x;
    __shared__ float sm[8 * DD];
    if (bi < 32) {
        int b = bi;
        float* hsb = sm;
        float* gs = sm + DD;
        hsb[tid] = hs[b * DD + tid];
        hsb[tid + 256] = hs[b * DD + tid + 256];
        __syncthreads();
        float a0 = bias[tid], a1 = bias[tid + 256];
        #pragma unroll 4
        for (int d = 0; d < DD; ++d) {
            float h = hsb[d];
            a0 = fmaf(h, W[(size_t)d * HH + tid], a0);
            a1 = fmaf(h, W[(size_t)d * HH + tid + 256], a1);
        }
        gs[tid] = a0;
        gs[tid + 256] = a1;
        __syncthreads();
        float c0 = ba[tid], c1 = ba[tid + 256];
        #pragma unroll 4
        for (int h = 0; h < HH; ++h) {
            float g = gs[h];
            c0 = fmaf(g, Wa[(size_t)h * HH + tid], c0);
            c1 = fmaf(g, Wa[(size_t)h * HH + tid + 256], c1);
        }
        cvec[b * HH + tid] = c0;
        cvec[b * HH + tid + 256] = c1;
    } else {
        int d0 = (bi - 32) * 8;
        float (*Us)[DD] = (float (*)[DD])sm;
        #pragma unroll
        for (int i = 0; i < 16; ++i) {
            int idx = i * 256 + tid;
            Us[idx >> 9][idx & 511] = U[(size_t)(d0 + (idx >> 9)) * HH + (idx & 511)];
        }
        __syncthreads();
        float acc[8][2] = {};
        #pragma unroll 2
        for (int h = 0; h < DD; ++h) {
            float w0 = Wa[(size_t)h * HH + tid];
            float w1 = Wa[(size_t)h * HH + 256 + tid];
            #pragma unroll
            for (int dd = 0; dd < 8; ++dd) {
                float u = Us[dd][h];
                acc[dd][0] = fmaf(u, w0, acc[dd][0]);
                acc[dd][1] = fmaf(u, w1, acc[dd][1]);
            }
        }
        #pragma unroll
        for (int dd = 0; dd < 8; ++dd) {
            UWaT[(size_t)tid * DD + d0 + dd] = f2bf_rne(acc[dd][0]);
            UWaT[(size_t)(tid + 256) * DD + d0 + dd] = f2bf_rne(acc[dd][1]);
        }
    }
}

// ---------------------------------------------------------------------------
// GEMM, m97 structure: 128(M) x 128(N) tile, BK=64, 256 thr = 4 waves in 2x2
// (wave w: rows wm=(w>>1)*64, cols wn=(w&1)*64; 4x4 frags of 16x16x32 bf16).
// Both A (ebf) and B (UWaT) staged per k0 via global_load_lds width=16:
// one instr = 8 rows x 8 16B-chunks (8 cachelines), lane l=(rl=l>>3, gg=l&7)
// reads chunk gg^rl -> LDS unit(row,slot) = row*8 + slot holds chunk
// g = slot ^ (row&7)  (R3-proven: coalesced staging + 0-conflict b128 reads).
// blockIdx = mt*4 + nt (nt fastest -> 4 siblings share the A-tile via L2/L3).
__global__ void k_gemm_tanh(
    const unsigned short* __restrict__ ebf, const unsigned short* __restrict__ Bt,
    const float* __restrict__ cvec, const float* __restrict__ V,
    float* __restrict__ cijp) {
    int tid = threadIdx.x;
    int nt = blockIdx.x & 3;
    int m0 = (blockIdx.x >> 2) * 128;
    int n0 = nt * 128;
    int lane = tid & 63, w = tid >> 6;
    int wm = (w >> 1) * 64, wn = (w & 1) * 64;
    int lcol = lane & 15, q = lane >> 4;
    int rl = lane >> 3, gg = lane & 7;

    __shared__ __align__(16) unsigned short As[128 * 64];   // 16 KB
    __shared__ __align__(16) unsigned short Bs[128 * 64];   // 16 KB

    f32x4 acc[4][4] = {};

    // per-wave staging bases: wave w stages rows [w*32, w*32+32) of each tile
    const unsigned short* Ab = ebf + (size_t)(m0 + w * 32 + rl) * DD + ((gg ^ rl) << 3);
    const unsigned short* Bb = Bt + (size_t)(n0 + w * 32 + rl) * DD + ((gg ^ rl) << 3);

    for (int k0 = 0; k0 < DD; k0 += 64) {
        if (k0) __syncthreads();           // barrier 1: prev tiles fully consumed
        #pragma unroll
        for (int u = 0; u < 4; ++u) {
            gload_lds16(Ab + (size_t)(u * 8) * DD + k0, &As[(w * 32 + u * 8) * 64]);
            gload_lds16(Bb + (size_t)(u * 8) * DD + k0, &Bs[(w * 32 + u * 8) * 64]);
        }
        __syncthreads();                   // barrier 2: drains load_lds
        #pragma unroll
        for (int ks = 0; ks < 2; ++ks) {
            int gk = ks * 4;
            s16x8 af[4], bfr[4];
            #pragma unroll
            for (int i = 0; i < 4; ++i) {
                int row = wm + i * 16 + lcol;
                af[i] = *(const s16x8*)&As[(row * 8 + ((gk + q) ^ (row & 7))) * 8];
            }
            #pragma unroll
            for (int j = 0; j < 4; ++j) {
                int col = wn + j * 16 + lcol;
                bfr[j] = *(const s16x8*)&Bs[(col * 8 + ((gk + q) ^ (col & 7))) * 8];
            }
            #pragma unroll
            for (int i = 0; i < 4; ++i)
                #pragma unroll
                for (int j = 0; j < 4; ++j)
                    acc[i][j] = __builtin_amdgcn_mfma_f32_16x16x32_bf16(
                        af[i], bfr[j], acc[i][j], 0, 0, 0);
        }
    }

    // Epilogue: partial cij over this block's 128 cols, no atomics.
    // C/D layout: col = lane&15, row = (lane>>4)*4 + reg  [verified R1..R7].
    __syncthreads();
    float* red = (float*)As;               // [4 waves][64 rows]
    int b = m0 >> 12;
    float cvv[4], Vv[4];
    #pragma unroll
    for (int j = 0; j < 4; ++j) {
        int h = n0 + wn + j * 16 + lcol;
        cvv[j] = cvec[b * HH + h];
        Vv[j] = V[h];
    }
    #pragma unroll
    for (int i = 0; i < 4; ++i) {
        #pragma unroll
        for (int r = 0; r < 4; ++r) {
            float s = 0.0f;
            #pragma unroll
            for (int j = 0; j < 4; ++j)
                s = fmaf(tanh_fast(acc[i][j][r] + cvv[j]), Vv[j], s);
            s += __shfl_xor(s, 1);
            s += __shfl_xor(s, 2);
            s += __shfl_xor(s, 4);
            s += __shfl_xor(s, 8);
            if (lcol == 0)
                red[w * 64 + i * 16 + q * 4 + r] = s;
        }
    }
    __syncthreads();
    if (tid < 128) {
        int half = tid >> 6, row = tid & 63;
        cijp[(size_t)nt * MM + m0 + half * 64 + row] =
            red[(half * 2) * 64 + row] + red[(half * 2 + 1) * 64 + row];
    }
}

// ---------------------------------------------------------------------------
// softmax over T per batch; folds the 4 n-tile partials.
__global__ void k_softmax(const float* __restrict__ cijp, float* __restrict__ alphas) {
    int b = blockIdx.x, tid = threadIdx.x;
    const float* r0 = cijp + (size_t)b * TT;
    __shared__ float red[4];
    __shared__ float rowbuf[TT];
    float m = -1e30f;
    for (int t = tid; t < TT; t += 256) {
        float v = r0[t] + r0[MM + t] + r0[2 * MM + t] + r0[3 * MM + t];
        rowbuf[t] = v;
        m = fmaxf(m, v);
    }
    #pragma unroll
    for (int o = 1; o < 64; o <<= 1) m = fmaxf(m, __shfl_xor(m, o));
    if ((tid & 63) == 0) red[tid >> 6] = m;
    __syncthreads();
    m = fmaxf(fmaxf(red[0], red[1]), fmaxf(red[2], red[3]));
    __syncthreads();
    float sum = 0.0f;
    for (int t = tid; t < TT; t += 256) {
        float v = __expf(rowbuf[t] - m);
        rowbuf[t] = v;
        sum += v;
    }
    #pragma unroll
    for (int o = 1; o < 64; o <<= 1) sum += __shfl_xor(sum, o);
    if ((tid & 63) == 0) red[tid >> 6] = sum;
    __syncthreads();
    float inv = 1.0f / (red[0] + red[1] + red[2] + red[3]);
    for (int t = tid; t < TT; t += 256)
        alphas[(size_t)b * TT + t] = rowbuf[t] * inv;
}

// ---------------------------------------------------------------------------
// partial weighted sums from the bf16 e copy (134 MB). block = (b, 64-t chunk);
// 64 threads x 8 cols, 4 t-streams. No atomics.
__global__ void k_wsum(const unsigned short* __restrict__ ebf,
                       const float* __restrict__ alphas, float* __restrict__ pw) {
    int b = blockIdx.x >> 6;
    int chunk = blockIdx.x & 63;
    int tid = threadIdx.x;
    int rg = tid >> 6, f8 = tid & 63;
    const unsigned short* base =
        ebf + (size_t)b * TT * DD + (size_t)chunk * 64 * DD + f8 * 8;
    const float* al = alphas + (size_t)b * TT + chunk * 64;
    float a8[8] = {};
    for (int it = 0; it < 16; ++it) {
        int t = it * 4 + rg;
        float a = al[t];
        uint4 v = *(const uint4*)(base + (size_t)t * DD);
        FU f;
        f.u = v.x << 16;          a8[0] = fmaf(a, f.f, a8[0]);
        f.u = v.x & 0xffff0000u;  a8[1] = fmaf(a, f.f, a8[1]);
        f.u = v.y << 16;          a8[2] = fmaf(a, f.f, a8[2]);
        f.u = v.y & 0xffff0000u;  a8[3] = fmaf(a, f.f, a8[3]);
        f.u = v.z << 16;          a8[4] = fmaf(a, f.f, a8[4]);
        f.u = v.z & 0xffff0000u;  a8[5] = fmaf(a, f.f, a8[5]);
        f.u = v.w << 16;          a8[6] = fmaf(a, f.f, a8[6]);
        f.u = v.w & 0xffff0000u;  a8[7] = fmaf(a, f.f, a8[7]);
    }
    __shared__ float red[3 * 512];
    if (rg > 0) {
        #pragma unroll
        for (int z = 0; z < 8; ++z) red[(rg - 1) * 512 + f8 * 8 + z] = a8[z];
    }
    __syncthreads();
    if (rg == 0) {
        #pragma unroll
        for (int z = 0; z < 8; ++z)
            a8[z] += red[f8 * 8 + z] + red[512 + f8 * 8 + z] + red[1024 + f8 * 8 + z];
        float* o = pw + ((size_t)(b * 64 + chunk)) * DD + f8 * 8;
        #pragma unroll
        for (int z = 0; z < 8; ++z) o[z] = a8[z];
    }
}

// out[b,d] = sum_chunk pw[b][chunk][d].
__global__ void k_wred(const float* __restrict__ pw, float* __restrict__ out) {
    int b = blockIdx.x, tid = threadIdx.x;
    float2 acc = {0.0f, 0.0f};
    const float* base = pw + (size_t)b * 64 * DD;
    #pragma unroll 4
    for (int c = 0; c < 64; ++c) {
        float2 v = *(const float2*)(base + (size_t)c * DD + tid * 2);
        acc.x += v.x;
        acc.y += v.y;
    }
    *(float2*)&out[b * DD + tid * 2] = acc;
}

// ---------------------------------------------------------------------------
extern "C" void kernel_launch(void* const* d_in, const int* in_sizes, int n_in,
                              void* d_out, int out_size, void* d_ws, size_t ws_size,
                              hipStream_t stream) {
    const float* hs   = (const float*)d_in[0];   // [32,512]
    const float* e    = (const float*)d_in[1];   // [32,4096,512]
    const float* W    = (const float*)d_in[2];   // [512,512]
    const float* U    = (const float*)d_in[3];   // [512,512]
    const float* V    = (const float*)d_in[4];   // [512]
    const float* bias = (const float*)d_in[5];   // [512]
    const float* Wa   = (const float*)d_in[6];   // [512,512]
    const float* ba   = (const float*)d_in[7];   // [512]

    float* out    = (float*)d_out;               // [32,512] then alphas [32,4096]
    float* alphas = out + BB * DD;

    float*          cijp = (float*)d_ws;                              // 2 MB (4 partials)
    float*          cvec = (float*)((char*)d_ws + 2097152);           // 64 KB
    unsigned short* Bt   = (unsigned short*)((char*)d_ws + 2162688);  // 512 KB bf16
    float*          pw   = (float*)((char*)d_ws + 2686976);           // 4 MB
    unsigned short* ebf  = (unsigned short*)((char*)d_ws + 6881280);  // 134.2 MB bf16

    // no memsets: every workspace word consumed is written first.

    k_conv<<<4096, 256, 0, stream>>>(e, ebf);
    k_prep<<<96, 256, 0, stream>>>(hs, W, bias, Wa, ba, U, cvec, Bt);
    k_gemm_tanh<<<4096, 256, 0, stream>>>(ebf, Bt, cvec, V, cijp);
    k_softmax<<<BB, 256, 0, stream>>>(cijp, alphas);
    k_wsum<<<BB * 64, 256, 0, stream>>>(ebf, alphas, pw);
    k_wred<<<BB, 256, 0, stream>>>(pw, out);
}